// Round 7
// baseline (147.970 us; speedup 1.0000x reference)
//
#include <hip/hip_runtime.h>
#include <hip/hip_bf16.h>
#include <math.h>

// ProxyGML: B=1024, DIM=512, C=1000, N=8
#define PB   1024
#define PDIM 512
#define PC   1000
#define PN   8
#define PCN  8000
#define PTOPK 400
#define NONPOS_K 392

typedef __bf16 bf16x8 __attribute__((ext_vector_type(8)));
typedef __bf16 bf16x4 __attribute__((ext_vector_type(4)));
typedef float  f32x4  __attribute__((ext_vector_type(4)));

__device__ static inline void async_load16(const __bf16* g, __bf16* l) {
    __builtin_amdgcn_global_load_lds(
        (const __attribute__((address_space(1))) void*)g,
        (__attribute__((address_space(3))) void*)l,
        16, 0, 0);
}

__device__ static inline unsigned bf16bits(float v) {
    __bf16 b = (__bf16)v;
    unsigned short u;
    __builtin_memcpy(&u, &b, 2);
    return (unsigned)u;
}

// key (16-bit, order-preserving) -> float. key = sign? ~u : u|0x8000.
__device__ static inline float keyf(unsigned t) {
    unsigned bits = (t & 0x8000u) ? ((t & 0x7fffu) << 16)
                                  : ((~t & 0xffffu) << 16);
    float f;
    __builtin_memcpy(&f, &bits, 4);
    return f;
}

// ----------------------------------------------------------------- prep ---
// bid<125  : fat block — owns 64 full columns of P. Pass0: column ssq from
//            global (coalesced). Pass2: 8 chunked 64x64 padded-LDS
//            transposes producing normalized Pt rows + fused per-class ccls
//            sums. Second P read is block-local -> L2-hot.
// 125..636 : x -> bf16 (float4 -> bf16x4).
// 637+     : zero esum/diag (16000 f32), ccls pad rows, acc.
__global__ __launch_bounds__(256) void k_prep(const float* __restrict__ x,
                                              const float* __restrict__ P,
                                              __bf16* __restrict__ xb,
                                              __bf16* __restrict__ Pt,
                                              __bf16* __restrict__ ccls,
                                              float* __restrict__ esd,
                                              float* __restrict__ padf,
                                              float* __restrict__ acc) {
    int bid = blockIdx.x, tid = threadIdx.x;
    if (bid < 125) {
        __shared__ float t[64][65];
        __shared__ float red[4][64];
        __shared__ float sinv[64];
        int j0 = bid * 64;
        int tx = tid & 63, ty = tid >> 6;
        // pass 0: column sum-of-squares, thread (tx=j-lane, ty=d-chunk/4)
        {
            const float* pc = P + (size_t)(ty * 128) * PCN + j0 + tx;
            float ss = 0.f;
#pragma unroll 8
            for (int k = 0; k < 128; ++k) {
                float v = pc[(size_t)k * PCN];
                ss = fmaf(v, v, ss);
            }
            red[ty][tx] = ss;
        }
        __syncthreads();
        if (tid < 64) {
            float sq = red[0][tid] + red[1][tid] + red[2][tid] + red[3][tid];
            sinv[tid] = 1.0f / fmaxf(sqrtf(sq), 1e-12f);
        }
        // pass 2: chunked transpose + normalize + ccls
        for (int dc = 0; dc < 8; ++dc) {
            __syncthreads();                    // sinv ready / t reusable
#pragma unroll
            for (int rr = 0; rr < 16; ++rr) {
                int d = dc * 64 + ty * 16 + rr;
                t[ty * 16 + rr][tx] = P[(size_t)d * PCN + j0 + tx];
            }
            __syncthreads();
            float cs0 = 0.f, cs1 = 0.f;
#pragma unroll
            for (int rr = 0; rr < 16; ++rr) {
                int jj = ty * 16 + rr;
                float val = t[tx][jj] * sinv[jj];
                Pt[(size_t)(j0 + jj) * PDIM + dc * 64 + tx] = (__bf16)val;
                if (rr < 8) cs0 += val; else cs1 += val;
            }
            int c0 = (j0 >> 3) + ty * 2;        // 16 j's = 2 whole classes
            ccls[(size_t)c0 * PDIM + dc * 64 + tx] = (__bf16)cs0;
            ccls[(size_t)(c0 + 1) * PDIM + dc * 64 + tx] = (__bf16)cs1;
        }
    } else if (bid < 637) {
        int i = (bid - 125) * 256 + tid;        // 131072 float4s total
        float4 v = ((const float4*)x)[i];
        bf16x4 o;
        o[0] = (__bf16)v.x; o[1] = (__bf16)v.y; o[2] = (__bf16)v.z; o[3] = (__bf16)v.w;
        ((bf16x4*)xb)[i] = o;
    } else {
        if (bid == 637 && tid < 16) acc[tid] = 0.f;
        int i = (bid - 637) * 256 + tid;        // 88 blocks cover 22144
        if (i < 16000) esd[i] = 0.f;
        else if (i < 16000 + 6144) padf[i - 16000] = 0.f;  // 24x512 bf16 pad
    }
}

// ------------- 256^2-tile counted-vmcnt GEMM (two GEMMs by block id) ------
// bid<128 : sim[m][j]  = xb(1024x512) . Pt(8000x512)^T   (NT form)
// bid>=128: clog[j][c] = Pt(8000x512) . ccls(1024x512)^T (NT form)
// BM=BN=256, BK=64, 8 waves (2Mx4N), per-wave 128x64 out, 128 KiB LDS dbuf.
// LDS tiles are [256 rows][8 slots of 16B]; physical slot = logical ^ (row&7).
// global_load_lds writes linearly; XOR applied to the GLOBAL source k-offset
// (rule 21: linear dest + inverse-swizzled source + swizzled read).
// Schedule per K-tile: lgkm(0); barrier; STAGE(kt+1); vmcnt(8); barrier;
// 2x { 12 ds_read_b128 ; setprio(1) ; 32 MFMA ; setprio(0) }.
__global__ __launch_bounds__(512, 2) void k_gemms2(const __bf16* __restrict__ xb,
                                                   const __bf16* __restrict__ Pt,
                                                   const __bf16* __restrict__ ccls,
                                                   __bf16* __restrict__ simb,
                                                   float* __restrict__ esum,
                                                   float* __restrict__ diag) {
    __shared__ __align__(16) __bf16 As[2][256 * 64];   // 64 KiB
    __shared__ __align__(16) __bf16 Bs[2][256 * 64];   // 64 KiB

    int tid = threadIdx.x;
    int w = tid >> 6, lane = tid & 63;
    int wr = w >> 2, wc = w & 3;           // 2M x 4N waves
    int quad = lane >> 4, l15 = lane & 15;

    int bid = blockIdx.x;
    bool is_sim = bid < 128;
    int M0, N0, Amax, Bmax;
    const __bf16 *Ab, *Bb;
    if (is_sim) {
        int mt = bid >> 5, nt = bid & 31;  // 4 x 32 tiles
        M0 = mt * 256; N0 = nt * 256;
        Ab = xb; Bb = Pt; Amax = PB - 1; Bmax = PCN - 1;
    } else {
        int b2 = bid - 128;
        int mt = b2 >> 2, nt = b2 & 3;     // 32 x 4 tiles
        M0 = mt * 256; N0 = nt * 256;
        Ab = Pt; Bb = ccls; Amax = PCN - 1; Bmax = 1023;
    }

    f32x4 acc[8][4] = {};

#define STAGE(kt_) {                                                         \
    int k0_ = (kt_) * 64, bb_ = (kt_) & 1;                                   \
    _Pragma("unroll")                                                        \
    for (int p_ = 0; p_ < 4; ++p_) {                                         \
        int idx_ = p_ * 512 + tid;                                           \
        int row_ = idx_ >> 3, sp_ = idx_ & 7;                                \
        int gk_ = ((sp_ ^ (row_ & 7)) << 3) + k0_;                           \
        int ga_ = M0 + row_; if (ga_ > Amax) ga_ = Amax;                     \
        async_load16(Ab + (size_t)ga_ * PDIM + gk_, &As[bb_][idx_ * 8]);     \
        int gb_ = N0 + row_; if (gb_ > Bmax) gb_ = Bmax;                     \
        async_load16(Bb + (size_t)gb_ * PDIM + gk_, &Bs[bb_][idx_ * 8]);     \
    } }

    STAGE(0)
    for (int kt = 0; kt < 8; ++kt) {
        int cur = kt & 1;
        asm volatile("s_waitcnt lgkmcnt(0)" ::: "memory");
        __builtin_amdgcn_s_barrier();            // all reads of buf^1 done
        if (kt < 7) {
            STAGE(kt + 1)                        // -> buf^1 (nobody reads it now)
            asm volatile("s_waitcnt vmcnt(8)" ::: "memory");  // kt's 8 retired
        } else {
            asm volatile("s_waitcnt vmcnt(0)" ::: "memory");  // tail drain
        }
        __builtin_amdgcn_s_barrier();            // buf[cur] fully staged

#pragma unroll
        for (int ks = 0; ks < 2; ++ks) {
            bf16x8 af[8], bfr[4];
#pragma unroll
            for (int mi = 0; mi < 8; ++mi) {
                int row = wr * 128 + mi * 16 + l15;
                af[mi] = *(const bf16x8*)&As[cur][(row << 6) +
                         ((((ks << 2) + quad) ^ (row & 7)) << 3)];
            }
#pragma unroll
            for (int nj = 0; nj < 4; ++nj) {
                int row = wc * 64 + nj * 16 + l15;
                bfr[nj] = *(const bf16x8*)&Bs[cur][(row << 6) +
                          ((((ks << 2) + quad) ^ (row & 7)) << 3)];
            }
            __builtin_amdgcn_s_setprio(1);
#pragma unroll
            for (int mi = 0; mi < 8; ++mi)
#pragma unroll
                for (int nj = 0; nj < 4; ++nj)
                    acc[mi][nj] = __builtin_amdgcn_mfma_f32_16x16x32_bf16(
                        af[mi], bfr[nj], acc[mi][nj], 0, 0, 0);
            __builtin_amdgcn_s_setprio(0);
        }
    }
#undef STAGE

    if (is_sim) {
        // sim store: pair adjacent cols via shfl -> one dword store per pair.
#pragma unroll
        for (int mi = 0; mi < 8; ++mi) {
            int r0 = M0 + wr * 128 + mi * 16 + quad * 4;
#pragma unroll
            for (int nj = 0; nj < 4; ++nj) {
                int cc = N0 + wc * 64 + nj * 16 + l15;
#pragma unroll
                for (int r = 0; r < 4; ++r) {
                    unsigned p = bf16bits(acc[mi][nj][r]);
                    unsigned q = (unsigned)__shfl_xor((int)p, 1, 64);
                    if (((l15 & 1) == 0) && cc < PCN)
                        *(unsigned*)&simb[(size_t)(r0 + r) * PCN + cc] = p | (q << 16);
                }
            }
        }
    } else {
        // clog -> esum/diag (rows N-dim = classes, guard 1000; m-rows over CN)
#pragma unroll
        for (int mi = 0; mi < 8; ++mi) {
            int r0 = M0 + wr * 128 + mi * 16 + quad * 4;
            float psum[4] = {0.f, 0.f, 0.f, 0.f};
#pragma unroll
            for (int nj = 0; nj < 4; ++nj) {
                int cc = N0 + wc * 64 + nj * 16 + l15;
                bool cvalid = (cc < PC);
#pragma unroll
                for (int r = 0; r < 4; ++r) {
                    float v = acc[mi][nj][r];
                    psum[r] += cvalid ? expf(v) : 0.f;
                    int rr = r0 + r;
                    if (cvalid && rr < PCN && cc == (rr >> 3)) diag[rr] = v;
                }
            }
#pragma unroll
            for (int off = 1; off < 16; off <<= 1)
#pragma unroll
                for (int r = 0; r < 4; ++r)
                    psum[r] += __shfl_xor(psum[r], off, 64);
            if (l15 == 0) {
#pragma unroll
                for (int r = 0; r < 4; ++r) {
                    int rr = r0 + r;
                    if (rr < PCN) atomicAdd(&esum[rr], psum[r]);
                }
            }
        }
    }
}

// ------------------------------------------------------------- row loss ---
// Register-resident row; tau found by 16-step binary search over the bf16
// ordered-key space (uniform threshold, pure-VALU counts, no LDS atomics,
// no candidate collection, no O(m^2)). g/e and index-order tie resolution
// done with float compares — identical semantics to the verified version.
__global__ __launch_bounds__(256) void k_rowloss(const __bf16* __restrict__ sim,
                                                 const int* __restrict__ target,
                                                 float* __restrict__ acc) {
    __shared__ int cnts[2][4];
    __shared__ float redf[8];
    __shared__ unsigned wtot[4];
    __shared__ float s_et;

    int b = blockIdx.x, tid = threadIdx.x;
    int lane = tid & 63, wv = tid >> 6;
    const bf16x8* row8 = (const bf16x8*)(sim + (size_t)b * PCN);
    int targ = target[b];

    float pv[4][8];
    bool msk[4];
#pragma unroll
    for (int k = 0; k < 4; ++k) {
        int c = tid + 256 * k;
        msk[k] = (c < PC) && (c != targ);
        if (c < PC) {
            bf16x8 vv = row8[c];
#pragma unroll
            for (int n = 0; n < 8; ++n) pv[k][n] = (float)vv[n];
        } else {
#pragma unroll
            for (int n = 0; n < 8; ++n) pv[k][n] = 0.f;
        }
    }

    // binary search: tauk = max key t with count(masked v >= keyf(t)) >= K.
    unsigned t = 0;
    for (int bit = 15; bit >= 0; --bit) {
        float tf = keyf(t | (1u << bit));
        int cnt = 0;
#pragma unroll
        for (int k = 0; k < 4; ++k)
            if (msk[k]) {
#pragma unroll
                for (int n = 0; n < 8; ++n) cnt += (pv[k][n] >= tf) ? 1 : 0;
            }
        for (int off = 32; off; off >>= 1) cnt += __shfl_down(cnt, off, 64);
        if (lane == 0) cnts[bit & 1][wv] = cnt;
        __syncthreads();
        int tot = cnts[bit & 1][0] + cnts[bit & 1][1]
                + cnts[bit & 1][2] + cnts[bit & 1][3];
        if (tot >= NONPOS_K) t |= (1u << bit);
    }
    float tauf = keyf(t);

    // exact strictly-greater / equal counts (float domain, packed reduce)
    {
        int cg = 0, ce = 0;
#pragma unroll
        for (int k = 0; k < 4; ++k)
            if (msk[k]) {
#pragma unroll
                for (int n = 0; n < 8; ++n) {
                    cg += (pv[k][n] > tauf) ? 1 : 0;
                    ce += (pv[k][n] == tauf) ? 1 : 0;
                }
            }
        int pack = (cg << 16) | ce;
        for (int off = 32; off; off >>= 1) pack += __shfl_down(pack, off, 64);
        __syncthreads();                       // cnts reads done everywhere
        if (lane == 0) wtot[wv] = (unsigned)pack;
        __syncthreads();
    }
    int G = 0, E = 0;
#pragma unroll
    for (int w2 = 0; w2 < 4; ++w2) {
        G += (int)(wtot[w2] >> 16);
        E += (int)(wtot[w2] & 0xffffu);
    }
    int rem = NONPOS_K - G;                    // ties to include, index order
    bool all_eq = (rem >= E);

    // parallel tie offsets in class-index order
    int offs[4] = {0, 0, 0, 0};
    if (!all_eq) {
        unsigned chunk_base = 0;
#pragma unroll
        for (int k = 0; k < 4; ++k) {
            unsigned tn = 0;
            if (msk[k]) {
#pragma unroll
                for (int n = 0; n < 8; ++n) tn += (pv[k][n] == tauf) ? 1u : 0u;
            }
            unsigned inc = tn;                       // inclusive wave scan
#pragma unroll
            for (int step = 1; step < 64; step <<= 1) {
                unsigned u = __shfl_up(inc, step, 64);
                if (lane >= step) inc += u;
            }
            __syncthreads();
            if (lane == 63) wtot[wv] = inc;
            __syncthreads();
            unsigned base = 0;
#pragma unroll
            for (int w2 = 0; w2 < 4; ++w2) if (w2 < wv) base += wtot[w2];
            offs[k] = (int)(chunk_base + base + inc - tn);
            chunk_base += wtot[0] + wtot[1] + wtot[2] + wtot[3];
        }
    }

    // logits -> exp -> loss
    float psum = 0.f;
#pragma unroll
    for (int k = 0; k < 4; ++k) {
        int c = tid + 256 * k;
        if (c >= PC) continue;
        float lg = 0.f;
        if (c == targ) {
#pragma unroll
            for (int n = 0; n < 8; ++n) lg += pv[k][n];
        } else {
#pragma unroll
            for (int n = 0; n < 8; ++n) {
                float v = pv[k][n];
                bool sel = v > tauf;
                if (!sel && v == tauf) {
                    if (all_eq) sel = true;
                    else { sel = (offs[k] < rem); offs[k]++; }
                }
                if (sel) lg += v;
            }
        }
        float e = (lg != 0.0f) ? expf(lg) : 0.0f;
        psum += e;
        if (c == targ) s_et = e;
    }
    for (int off = 32; off; off >>= 1) psum += __shfl_down(psum, off, 64);
    if (lane == 0) redf[wv] = psum;
    __syncthreads();
    if (tid == 0) {
        float denom = 1e-8f + redf[0] + redf[1] + redf[2] + redf[3];
        atomicAdd(acc, -logf(s_et / denom + 1e-20f));
    }
}

// --------------------------------------------------------------- final ----
__global__ __launch_bounds__(256) void k_final(const float* __restrict__ esum,
                                               const float* __restrict__ diag,
                                               const float* __restrict__ acc,
                                               float* __restrict__ out) {
    __shared__ float redf[4];
    int tid = threadIdx.x, lane = tid & 63, wv = tid >> 6;
    float s = 0.f;
    for (int j = tid; j < PCN; j += 256)
        s += logf(esum[j]) - diag[j];
    for (int off = 32; off; off >>= 1) s += __shfl_down(s, off, 64);
    if (lane == 0) redf[wv] = s;
    __syncthreads();
    if (tid == 0) {
        float rg = (redf[0] + redf[1] + redf[2] + redf[3]) * (1.0f / PCN);
        float lc = acc[0] * (1.0f / PB);
        out[0] = lc + 0.3f * rg;
        out[1] = lc;
    }
}

// ---------------------------------------------------------------------------
extern "C" void kernel_launch(void* const* d_in, const int* in_sizes, int n_in,
                              void* d_out, int out_size, void* d_ws, size_t ws_size,
                              hipStream_t stream) {
    const float* x       = (const float*)d_in[0];   // (1024, 512)
    const float* proxies = (const float*)d_in[1];   // (512, 8000)
    const int*   target  = (const int*)d_in[2];     // (1024,)
    float* out = (float*)d_out;
    float* ws  = (float*)d_ws;

    // workspace layout (float offsets):
    //   acc    [0,      64)
    //   (gap)  [64,     64064)     unused
    //   esum   [64064,  72064)     8000 f32   } contiguous 16000 zeroed
    //   diag   [72064,  80064)     8000 f32   } together in k_prep
    //   xb     [80064,  342208)    1024x512 bf16
    //   cclsb  [342208, 604352)    1024x512 bf16 (rows 1000..1023 pad=0)
    //   Pt     [604352, 2652352)   8000x512 bf16
    //   simb   [2652352,6748352)   1024x8000 bf16
    float*  acc   = ws;
    float*  esum  = ws + 64064;
    float*  diag  = ws + 72064;
    __bf16* xb    = (__bf16*)(ws + 80064);
    __bf16* cclsb = (__bf16*)(ws + 342208);
    __bf16* Pt    = (__bf16*)(ws + 604352);
    __bf16* simb  = (__bf16*)(ws + 2652352);

    float* padf = (float*)cclsb + 256000;     // ccls rows 1000..1023 as f32

    k_prep<<<725, 256, 0, stream>>>(x, proxies, xb, Pt, cclsb, esum, padf, acc);
    k_gemms2<<<256, 512, 0, stream>>>(xb, Pt, cclsb, simb, esum, diag);
    k_rowloss<<<PB, 256, 0, stream>>>(simb, target, acc);
    k_final<<<1, 256, 0, stream>>>(esum, diag, acc, out);
}

// Round 8
// 140.471 us; speedup vs baseline: 1.0534x; 1.0534x over previous
//
#include <hip/hip_runtime.h>
#include <hip/hip_bf16.h>
#include <math.h>

// ProxyGML: B=1024, DIM=512, C=1000, N=8
#define PB   1024
#define PDIM 512
#define PC   1000
#define PN   8
#define PCN  8000
#define PTOPK 400
#define NONPOS_K 392
#define NBIN 1024

typedef __bf16 bf16x8 __attribute__((ext_vector_type(8)));
typedef __bf16 bf16x4 __attribute__((ext_vector_type(4)));
typedef float  f32x4  __attribute__((ext_vector_type(4)));

__device__ static inline void async_load16(const __bf16* g, __bf16* l) {
    __builtin_amdgcn_global_load_lds(
        (const __attribute__((address_space(1))) void*)g,
        (__attribute__((address_space(3))) void*)l,
        16, 0, 0);
}

__device__ static inline unsigned bf16bits(float v) {
    __bf16 b = (__bf16)v;
    unsigned short u;
    __builtin_memcpy(&u, &b, 2);
    return (unsigned)u;
}

// order-preserving 16-bit key for a value that is exactly a bf16
__device__ static inline unsigned bkey(float v) {
    unsigned u = bf16bits(v);
    return (u & 0x8000u) ? ((~u) & 0xffffu) : (u | 0x8000u);
}

// key -> float (inverse of bkey)
__device__ static inline float keyf(unsigned t) {
    unsigned bits = (t & 0x8000u) ? ((t & 0x7fffu) << 16)
                                  : ((~t & 0xffffu) << 16);
    float f;
    __builtin_memcpy(&f, &bits, 4);
    return f;
}

// ----------------------------------------------------------------- pre ----
// b<512: x->bf16. 512..767: P column-ssq partials. 768+: zero esum/diag and
// ccls pad rows (classes 1000..1023).
__global__ __launch_bounds__(256) void k_pre(const float* __restrict__ x,
                                             const float* __restrict__ P,
                                             __bf16* __restrict__ xb,
                                             float* __restrict__ ssqp,
                                             float* __restrict__ esd,
                                             float* __restrict__ padf,
                                             float* __restrict__ acc) {
    int b = blockIdx.x, tid = threadIdx.x;
    if (b == 0 && tid < 8) acc[tid] = 0.f;
    if (b < 512) {
        int i = b * 256 + tid;
        float4 v = ((const float4*)x)[i];
        bf16x4 o;
        o[0] = (__bf16)v.x; o[1] = (__bf16)v.y; o[2] = (__bf16)v.z; o[3] = (__bf16)v.w;
        ((bf16x4*)xb)[i] = o;
    } else if (b < 768) {
        int idx = b - 512;              // 0..255
        int slice = idx & 7, jb = idx >> 3;
        int j = jb * 256 + tid;
        if (j < PCN) {
            const float* p = P + (size_t)(slice * 64) * PCN + j;
            float ss = 0.f;
#pragma unroll 8
            for (int r = 0; r < 64; ++r) {
                float v = p[(size_t)r * PCN];
                ss = fmaf(v, v, ss);
            }
            ssqp[slice * PCN + j] = ss;
        }
    } else {
        int i = (b - 768) * 256 + tid;  // 0..22271
        if (i < 16000) esd[i] = 0.f;
        else if (i < 16000 + 6144) padf[i - 16000] = 0.f;  // 24x512 bf16 pad
    }
}

// ---------------- P (512x8000) -> Pt bf16 (8000x512) + fused ccls ---------
__global__ __launch_bounds__(256) void k_tpose(const float* __restrict__ P,
                                               const float* __restrict__ ssqp,
                                               __bf16* __restrict__ Pt,
                                               __bf16* __restrict__ ccls) {
    __shared__ float t[64][65];
    __shared__ float sinv[64];
    int tid = threadIdx.x;
    int tx = tid & 63, ty = tid >> 6;
    int j0 = blockIdx.x * 64, d0 = blockIdx.y * 64;
    if (tid < 64) {
        float sq = 0.f;
#pragma unroll
        for (int p2 = 0; p2 < 8; ++p2) sq += ssqp[p2 * PCN + j0 + tid];
        sinv[tid] = 1.0f / fmaxf(sqrtf(sq), 1e-12f);
    }
#pragma unroll
    for (int r = 0; r < 16; ++r) {
        int d = d0 + ty * 16 + r;
        t[ty * 16 + r][tx] = P[(size_t)d * PCN + j0 + tx];
    }
    __syncthreads();
    float cs0 = 0.f, cs1 = 0.f;
#pragma unroll
    for (int r = 0; r < 16; ++r) {
        int jl = ty * 16 + r;
        float val = t[tx][jl] * sinv[jl];
        Pt[(size_t)(j0 + jl) * PDIM + d0 + tx] = (__bf16)val;
        if (r < 8) cs0 += val; else cs1 += val;
    }
    int c0 = (j0 >> 3) + ty * 2;           // 16 j's = 2 whole classes
    ccls[(size_t)c0 * PDIM + d0 + tx] = (__bf16)cs0;
    ccls[(size_t)(c0 + 1) * PDIM + d0 + tx] = (__bf16)cs1;
}

// ------------- 256^2-tile counted-vmcnt GEMM (two GEMMs by block id) ------
// bid<128 : sim[m][j]  = xb(1024x512) . Pt(8000x512)^T   (NT form)
// bid>=128: clog[j][c] = Pt(8000x512) . ccls(1024x512)^T (NT form)
// BM=BN=256, BK=64, 8 waves (2Mx4N), per-wave 128x64 out, 128 KiB LDS dbuf.
// LDS tiles are [256 rows][8 slots of 16B]; physical slot = logical ^ (row&7).
// global_load_lds writes linearly; XOR applied to the GLOBAL source k-offset
// (rule 21: linear dest + inverse-swizzled source + swizzled read).
// Schedule per K-tile: lgkm(0); barrier; STAGE(kt+1); vmcnt(8); barrier;
// 2x { 12 ds_read_b128 ; setprio(1) ; 32 MFMA ; setprio(0) }.
__global__ __launch_bounds__(512, 2) void k_gemms2(const __bf16* __restrict__ xb,
                                                   const __bf16* __restrict__ Pt,
                                                   const __bf16* __restrict__ ccls,
                                                   __bf16* __restrict__ simb,
                                                   float* __restrict__ esum,
                                                   float* __restrict__ diag) {
    __shared__ __align__(16) __bf16 As[2][256 * 64];   // 64 KiB
    __shared__ __align__(16) __bf16 Bs[2][256 * 64];   // 64 KiB

    int tid = threadIdx.x;
    int w = tid >> 6, lane = tid & 63;
    int wr = w >> 2, wc = w & 3;           // 2M x 4N waves
    int quad = lane >> 4, l15 = lane & 15;

    int bid = blockIdx.x;
    bool is_sim = bid < 128;
    int M0, N0, Amax, Bmax;
    const __bf16 *Ab, *Bb;
    if (is_sim) {
        int mt = bid >> 5, nt = bid & 31;  // 4 x 32 tiles
        M0 = mt * 256; N0 = nt * 256;
        Ab = xb; Bb = Pt; Amax = PB - 1; Bmax = PCN - 1;
    } else {
        int b2 = bid - 128;
        int mt = b2 >> 2, nt = b2 & 3;     // 32 x 4 tiles
        M0 = mt * 256; N0 = nt * 256;
        Ab = Pt; Bb = ccls; Amax = PCN - 1; Bmax = 1023;
    }

    f32x4 acc[8][4] = {};

#define STAGE(kt_) {                                                         \
    int k0_ = (kt_) * 64, bb_ = (kt_) & 1;                                   \
    _Pragma("unroll")                                                        \
    for (int p_ = 0; p_ < 4; ++p_) {                                         \
        int idx_ = p_ * 512 + tid;                                           \
        int row_ = idx_ >> 3, sp_ = idx_ & 7;                                \
        int gk_ = ((sp_ ^ (row_ & 7)) << 3) + k0_;                           \
        int ga_ = M0 + row_; if (ga_ > Amax) ga_ = Amax;                     \
        async_load16(Ab + (size_t)ga_ * PDIM + gk_, &As[bb_][idx_ * 8]);     \
        int gb_ = N0 + row_; if (gb_ > Bmax) gb_ = Bmax;                     \
        async_load16(Bb + (size_t)gb_ * PDIM + gk_, &Bs[bb_][idx_ * 8]);     \
    } }

    STAGE(0)
    for (int kt = 0; kt < 8; ++kt) {
        int cur = kt & 1;
        asm volatile("s_waitcnt lgkmcnt(0)" ::: "memory");
        __builtin_amdgcn_s_barrier();            // all reads of buf^1 done
        if (kt < 7) {
            STAGE(kt + 1)                        // -> buf^1 (nobody reads it now)
            asm volatile("s_waitcnt vmcnt(8)" ::: "memory");  // kt's 8 retired
        } else {
            asm volatile("s_waitcnt vmcnt(0)" ::: "memory");  // tail drain
        }
        __builtin_amdgcn_s_barrier();            // buf[cur] fully staged

#pragma unroll
        for (int ks = 0; ks < 2; ++ks) {
            bf16x8 af[8], bfr[4];
#pragma unroll
            for (int mi = 0; mi < 8; ++mi) {
                int row = wr * 128 + mi * 16 + l15;
                af[mi] = *(const bf16x8*)&As[cur][(row << 6) +
                         ((((ks << 2) + quad) ^ (row & 7)) << 3)];
            }
#pragma unroll
            for (int nj = 0; nj < 4; ++nj) {
                int row = wc * 64 + nj * 16 + l15;
                bfr[nj] = *(const bf16x8*)&Bs[cur][(row << 6) +
                          ((((ks << 2) + quad) ^ (row & 7)) << 3)];
            }
            __builtin_amdgcn_s_setprio(1);
#pragma unroll
            for (int mi = 0; mi < 8; ++mi)
#pragma unroll
                for (int nj = 0; nj < 4; ++nj)
                    acc[mi][nj] = __builtin_amdgcn_mfma_f32_16x16x32_bf16(
                        af[mi], bfr[nj], acc[mi][nj], 0, 0, 0);
            __builtin_amdgcn_s_setprio(0);
        }
    }
#undef STAGE

    if (is_sim) {
        // sim store: pair adjacent cols via shfl -> one dword store per pair.
#pragma unroll
        for (int mi = 0; mi < 8; ++mi) {
            int r0 = M0 + wr * 128 + mi * 16 + quad * 4;
#pragma unroll
            for (int nj = 0; nj < 4; ++nj) {
                int cc = N0 + wc * 64 + nj * 16 + l15;
#pragma unroll
                for (int r = 0; r < 4; ++r) {
                    unsigned p = bf16bits(acc[mi][nj][r]);
                    unsigned q = (unsigned)__shfl_xor((int)p, 1, 64);
                    if (((l15 & 1) == 0) && cc < PCN)
                        *(unsigned*)&simb[(size_t)(r0 + r) * PCN + cc] = p | (q << 16);
                }
            }
        }
    } else {
        // clog -> esum/diag (rows N-dim = classes, guard 1000; m-rows over CN)
#pragma unroll
        for (int mi = 0; mi < 8; ++mi) {
            int r0 = M0 + wr * 128 + mi * 16 + quad * 4;
            float psum[4] = {0.f, 0.f, 0.f, 0.f};
#pragma unroll
            for (int nj = 0; nj < 4; ++nj) {
                int cc = N0 + wc * 64 + nj * 16 + l15;
                bool cvalid = (cc < PC);
#pragma unroll
                for (int r = 0; r < 4; ++r) {
                    float v = acc[mi][nj][r];
                    psum[r] += cvalid ? expf(v) : 0.f;
                    int rr = r0 + r;
                    if (cvalid && rr < PCN && cc == (rr >> 3)) diag[rr] = v;
                }
            }
#pragma unroll
            for (int off = 1; off < 16; off <<= 1)
#pragma unroll
                for (int r = 0; r < 4; ++r)
                    psum[r] += __shfl_xor(psum[r], off, 64);
            if (l15 == 0) {
#pragma unroll
                for (int r = 0; r < 4; ++r) {
                    int rr = r0 + r;
                    if (rr < PCN) atomicAdd(&esum[rr], psum[r]);
                }
            }
        }
    }
}

// ------------------------------------------------------------- row loss ---
// Coarse 1024-bin histogram on the bf16 ordered key (key>>6, computed on the
// fly — no min/max pass, no persistent key registers), fine 64-bin histogram
// on key&63 within tau's coarse bin (no candidate collect, no O(m^2)).
// Tie offsets (index order) via ONE packed dual-16bit-field wave scan +
// single barrier (was 8 barriers).
__global__ __launch_bounds__(256) void k_rowloss(const __bf16* __restrict__ sim,
                                                 const int* __restrict__ target,
                                                 float* __restrict__ acc) {
    __shared__ unsigned hist[NBIN];
    __shared__ unsigned hist2[64];
    __shared__ float redf[4];
    __shared__ unsigned wtot[4];
    __shared__ unsigned wtot2[4][2];
    __shared__ unsigned s_cb, s_A, s_tauk, s_gt, s_eq;
    __shared__ float s_et;

    int b = blockIdx.x, tid = threadIdx.x;
    int lane = tid & 63, wv = tid >> 6;
    const bf16x8* row8 = (const bf16x8*)(sim + (size_t)b * PCN);
    int targ = target[b];

#pragma unroll
    for (int k = 0; k < 4; ++k) hist[tid + 256 * k] = 0u;
    if (tid < 64) hist2[tid] = 0u;

    float pv[4][8];
    bool msk[4];
#pragma unroll
    for (int k = 0; k < 4; ++k) {
        int c = tid + 256 * k;
        msk[k] = (c < PC) && (c != targ);
        if (c < PC) {
            bf16x8 vv = row8[c];
#pragma unroll
            for (int n = 0; n < 8; ++n) pv[k][n] = (float)vv[n];
        } else {
#pragma unroll
            for (int n = 0; n < 8; ++n) pv[k][n] = 0.f;
        }
    }
    __syncthreads();                       // hist zeros visible

    // coarse histogram on key>>6
#pragma unroll
    for (int k = 0; k < 4; ++k)
        if (msk[k]) {
#pragma unroll
            for (int n = 0; n < 8; ++n)
                atomicAdd(&hist[bkey(pv[k][n]) >> 6], 1u);
        }
    __syncthreads();

    // suffix scan over 1024 coarse bins (high key = high bin first)
    int b0 = tid * 4;
    unsigned h0 = hist[b0], h1 = hist[b0 + 1], h2 = hist[b0 + 2], h3 = hist[b0 + 3];
    unsigned l3 = h3, l2 = h2 + l3, l1 = h1 + l2, l0 = h0 + l1;
    unsigned T = l0;
#pragma unroll
    for (int step = 1; step < 64; step <<= 1) {
        unsigned u = __shfl_down(T, step, 64);
        if (lane + step < 64) T += u;
    }
    if (lane == 0) wtot[wv] = T;
    __syncthreads();
    unsigned tail = 0;
#pragma unroll
    for (int w2 = 0; w2 < 4; ++w2) if (w2 > wv) tail += wtot[w2];
    unsigned E = T - l0 + tail;
    {
        unsigned sfx[4] = {l0 + E, l1 + E, l2 + E, l3 + E};
        unsigned nxt[4] = {l1 + E, l2 + E, l3 + E, E};
#pragma unroll
        for (int i = 0; i < 4; ++i)
            if (sfx[i] >= NONPOS_K && nxt[i] < NONPOS_K) {
                s_cb = (unsigned)(b0 + i);
                s_A = nxt[i];              // count in strictly-greater bins
            }
    }
    __syncthreads();
    unsigned cb = s_cb, A = s_A;

    // fine histogram on key&63 within coarse bin cb
#pragma unroll
    for (int k = 0; k < 4; ++k)
        if (msk[k]) {
#pragma unroll
            for (int n = 0; n < 8; ++n) {
                unsigned kk = bkey(pv[k][n]);
                if ((kk >> 6) == cb) atomicAdd(&hist2[kk & 63u], 1u);
            }
        }
    __syncthreads();

    // wave-0 suffix scan over 64 fine bins -> exact tau key, g, e
    if (wv == 0) {
        unsigned h = hist2[lane];
        unsigned sfx = h;
#pragma unroll
        for (int step = 1; step < 64; step <<= 1) {
            unsigned u = __shfl_down(sfx, step, 64);
            if (lane + step < 64) sfx += u;
        }
        unsigned nxt = sfx - h;
        if (A + sfx >= NONPOS_K && A + nxt < NONPOS_K) {
            s_tauk = (cb << 6) | (unsigned)lane;
            s_gt = A + nxt;                // strictly greater than tau
            s_eq = h;                      // equal to tau
        }
    }
    __syncthreads();
    float tauf = keyf(s_tauk);
    int rem = NONPOS_K - (int)s_gt;        // ties to include, by index order
    bool all_eq = (rem >= (int)s_eq);

    // tie offsets in class-index order: packed dual-field scan, ONE barrier.
    // fields: p01 = tn0 | tn1<<16, p23 = tn2 | tn3<<16 (per-wave tot <= 512).
    int offs[4] = {0, 0, 0, 0};
    if (!all_eq) {
        unsigned tn[4];
#pragma unroll
        for (int k = 0; k < 4; ++k) {
            unsigned t = 0;
            if (msk[k]) {
#pragma unroll
                for (int n = 0; n < 8; ++n) t += (pv[k][n] == tauf) ? 1u : 0u;
            }
            tn[k] = t;
        }
        unsigned p01 = tn[0] | (tn[1] << 16), p23 = tn[2] | (tn[3] << 16);
        unsigned i01 = p01, i23 = p23;
#pragma unroll
        for (int step = 1; step < 64; step <<= 1) {
            unsigned u0 = __shfl_up(i01, step, 64);
            unsigned u1 = __shfl_up(i23, step, 64);
            if (lane >= step) { i01 += u0; i23 += u1; }
        }
        if (lane == 63) { wtot2[wv][0] = i01; wtot2[wv][1] = i23; }
        __syncthreads();
        unsigned base01 = 0, base23 = 0, t01 = 0, t23 = 0;
#pragma unroll
        for (int w2 = 0; w2 < 4; ++w2) {
            if (w2 < wv) { base01 += wtot2[w2][0]; base23 += wtot2[w2][1]; }
            t01 += wtot2[w2][0]; t23 += wtot2[w2][1];
        }
        unsigned e01 = i01 - p01, e23 = i23 - p23;   // exclusive within wave
        unsigned tot0 = t01 & 0xffffu, tot1 = t01 >> 16, tot2 = t23 & 0xffffu;
        offs[0] = (int)((base01 & 0xffffu) + (e01 & 0xffffu));
        offs[1] = (int)(tot0 + (base01 >> 16) + (e01 >> 16));
        offs[2] = (int)(tot0 + tot1 + (base23 & 0xffffu) + (e23 & 0xffffu));
        offs[3] = (int)(tot0 + tot1 + tot2 + (base23 >> 16) + (e23 >> 16));
    }

    // logits -> exp -> loss
    float psum = 0.f;
#pragma unroll
    for (int k = 0; k < 4; ++k) {
        int c = tid + 256 * k;
        if (c >= PC) continue;
        float lg = 0.f;
        if (c == targ) {
#pragma unroll
            for (int n = 0; n < 8; ++n) lg += pv[k][n];
        } else {
#pragma unroll
            for (int n = 0; n < 8; ++n) {
                float v = pv[k][n];
                bool sel = v > tauf;
                if (!sel && v == tauf) {
                    if (all_eq) sel = true;
                    else { sel = (offs[k] < rem); offs[k]++; }
                }
                if (sel) lg += v;
            }
        }
        float e = (lg != 0.0f) ? __expf(lg) : 0.0f;
        psum += e;
        if (c == targ) s_et = e;
    }
    for (int off = 32; off; off >>= 1) psum += __shfl_down(psum, off, 64);
    if (lane == 0) redf[wv] = psum;
    __syncthreads();
    if (tid == 0) {
        float denom = 1e-8f + redf[0] + redf[1] + redf[2] + redf[3];
        atomicAdd(acc, -logf(s_et / denom + 1e-20f));
    }
}

// --------------------------------------------------------------- final ----
__global__ __launch_bounds__(256) void k_final(const float* __restrict__ esum,
                                               const float* __restrict__ diag,
                                               const float* __restrict__ acc,
                                               float* __restrict__ out) {
    __shared__ float redf[4];
    int tid = threadIdx.x, lane = tid & 63, wv = tid >> 6;
    float s = 0.f;
    for (int j = tid; j < PCN; j += 256)
        s += logf(esum[j]) - diag[j];
    for (int off = 32; off; off >>= 1) s += __shfl_down(s, off, 64);
    if (lane == 0) redf[wv] = s;
    __syncthreads();
    if (tid == 0) {
        float rg = (redf[0] + redf[1] + redf[2] + redf[3]) * (1.0f / PCN);
        float lc = acc[0] * (1.0f / PB);
        out[0] = lc + 0.3f * rg;
        out[1] = lc;
    }
}

// ---------------------------------------------------------------------------
extern "C" void kernel_launch(void* const* d_in, const int* in_sizes, int n_in,
                              void* d_out, int out_size, void* d_ws, size_t ws_size,
                              hipStream_t stream) {
    const float* x       = (const float*)d_in[0];   // (1024, 512)
    const float* proxies = (const float*)d_in[1];   // (512, 8000)
    const int*   target  = (const int*)d_in[2];     // (1024,)
    float* out = (float*)d_out;
    float* ws  = (float*)d_ws;

    // workspace layout (float offsets):
    //   acc    [0,      64)
    //   ssqp   [64,     64064)     8x8000 f32
    //   esum   [64064,  72064)     8000 f32   } contiguous 16000 zeroed
    //   diag   [72064,  80064)     8000 f32   } together in k_pre
    //   xb     [80064,  342208)    1024x512 bf16
    //   cclsb  [342208, 604352)    1024x512 bf16 (rows 1000..1023 pad=0)
    //   Pt     [604352, 2652352)   8000x512 bf16
    //   simb   [2652352,6748352)   1024x8000 bf16
    float*  acc   = ws;
    float*  ssqp  = ws + 64;
    float*  esum  = ws + 64064;
    float*  diag  = ws + 72064;
    __bf16* xb    = (__bf16*)(ws + 80064);
    __bf16* cclsb = (__bf16*)(ws + 342208);
    __bf16* Pt    = (__bf16*)(ws + 604352);
    __bf16* simb  = (__bf16*)(ws + 2652352);

    float* padf = (float*)cclsb + 256000;     // ccls rows 1000..1023 as f32

    k_pre<<<856, 256, 0, stream>>>(x, proxies, xb, ssqp, esum, padf, acc);
    k_tpose<<<dim3(125, 8), 256, 0, stream>>>(proxies, ssqp, Pt, cclsb);
    k_gemms2<<<256, 512, 0, stream>>>(xb, Pt, cclsb, simb, esum, diag);
    k_rowloss<<<PB, 256, 0, stream>>>(simb, target, acc);
    k_final<<<1, 256, 0, stream>>>(esum, diag, acc, out);
}